// Round 3
// baseline (233.553 us; speedup 1.0000x reference)
//
#include <hip/hip_runtime.h>
#include <math.h>

// Problem constants (match reference)
#define B 32
#define C 4
#define P (360*640)        // 230400 pixels per batch
#define L 5                // MAX_LANES
#define DELTA_V 1.0f
#define DELTA_D 6.0f

// R10 shape: latency-bound fix — big grids, small blocks, low VGPR.
#define CH1 225            // chunks per batch; each block covers 1024 px
#define PSTR 228           // padded chunk-stride of value-major partials
#define NBLK3 (B*CH1)      // 7200 pull partials

__device__ __forceinline__ float waveReduce(float v) {
#pragma unroll
    for (int off = 32; off; off >>= 1) v += __shfl_down(v, off, 64);
    return v;
}

// ---------------------------------------------------------------------------
// Kernel 1: segment sums, CHANNEL-PER-WAVE (R10). Block = 1024 px of batch b;
// wave w accumulates channel w over those pixels (labels re-read per wave are
// L1 hits — no extra L2 traffic). Per thread: 4 int4 + 4 float4 hoisted (8
// outstanding loads) + 10 accumulators (5 sums + 5 counts) ~= 60 VGPR ->
// 8 waves/SIMD. Grid 225x32 = 7200 blocks (28 blocks/CU of work): fixes R9's
// 18% occupancy / 1440-block concurrency failure. Counts identical across
// waves -> wave 0's are used. Wave 0 also emits packed uint8 labels for K2.
// Partials VALUE-MAJOR: partial[(b*25+v)*PSTR+x], v = c*5+l (sums), 20+l (cnt).
// ---------------------------------------------------------------------------
__global__ __launch_bounds__(256, 2) void seg_sums_k(const int* __restrict__ tgt,
                                                     const float* __restrict__ emb,
                                                     float* __restrict__ partial,
                                                     unsigned char* __restrict__ tpk) {
    const int x = blockIdx.x, b = blockIdx.y;
    const int tid = threadIdx.x;
    const int lane = tid & 63, wave = tid >> 6;

    const int4*   t4 = (const int4*)(tgt + (size_t)b * P);
    const float4* ec = (const float4*)(emb + ((size_t)b * C + wave) * P);
    uchar4*      tp4 = (uchar4*)(tpk + (size_t)b * P);

    // hoist all 8 loads (int4 x4 + float4 x4) — 8 outstanding per thread
    int4   tv[4];
    float4 ev[4];
#pragma unroll
    for (int it = 0; it < 4; ++it) {
        const int g = x * 256 + it * 64 + lane;   // int4/float4 index in batch
        tv[it] = t4[g];
        ev[it] = ec[g];
    }
    if (wave == 0) {
#pragma unroll
        for (int it = 0; it < 4; ++it) {
            const int g = x * 256 + it * 64 + lane;
            tp4[g] = make_uchar4((unsigned char)tv[it].x, (unsigned char)tv[it].y,
                                 (unsigned char)tv[it].z, (unsigned char)tv[it].w);
        }
    }

    float s[L], n[L];
#pragma unroll
    for (int l = 0; l < L; ++l) { s[l] = 0.f; n[l] = 0.f; }

    auto elem = [&](int tt, float v) {
#pragma unroll
        for (int l = 0; l < L; ++l) {
            float m = (tt == l + 1) ? 1.0f : 0.0f;
            n[l] += m;
            s[l] = fmaf(m, v, s[l]);
        }
    };
#pragma unroll
    for (int it = 0; it < 4; ++it) {
        elem(tv[it].x, ev[it].x);
        elem(tv[it].y, ev[it].y);
        elem(tv[it].z, ev[it].z);
        elem(tv[it].w, ev[it].w);
    }

    // ---- per-wave reduce of 10 values, cross-wave combine in LDS ----
    __shared__ float red[4][2 * L];
#pragma unroll
    for (int k = 0; k < 2 * L; ++k) {
        float r = waveReduce(k < L ? s[k] : n[k - L]);
        if (lane == 0) red[wave][k] = r;
    }
    __syncthreads();
    if (tid < 25) {
        // v<20: channel v/5's sum for lane v%5 (computed by wave v/5).
        // v>=20: counts (identical across waves; take wave 0's).
        const float r = (tid < 20) ? red[tid / 5][tid % 5] : red[0][L + (tid - 20)];
        partial[((size_t)b * 25 + tid) * PSTR + x] = r;
    }
}

// ---------------------------------------------------------------------------
// Kernel 1.5: reduce partials -> means/valid/counts (once per batch, not per
// pull block). 32 blocks x 256 threads; wave w reduces values w, w+4, ...
// ---------------------------------------------------------------------------
__global__ __launch_bounds__(256) void means_k(const float* __restrict__ partial,
                                               float* __restrict__ meansG,
                                               float* __restrict__ validG,
                                               float* __restrict__ cntvG) {
    __shared__ float praw[25];
    const int b = blockIdx.x;
    const int tid = threadIdx.x;
    const int lane = tid & 63, wave = tid >> 6;

    for (int v = wave; v < 25; v += 4) {
        float sum = 0.f;
        for (int i = lane; i < CH1; i += 64)
            sum += partial[((size_t)b * 25 + v) * PSTR + i];
        sum = waveReduce(sum);
        if (lane == 0) praw[v] = sum;
    }
    __syncthreads();
    if (tid < L) {
        const float cnt = praw[20 + tid];
        const bool  vld = cnt > 1.5f;          // integer count > 1
        const float inv = 1.0f / fmaxf(cnt, 1.0f);
        float4 m = make_float4(praw[tid] * inv, praw[5 + tid] * inv,
                               praw[10 + tid] * inv, praw[15 + tid] * inv);
        *(float4*)(meansG + ((size_t)b * L + tid) * 4) = m;
        validG[b * L + tid] = vld ? 1.f : 0.f;
        cntvG[b * L + tid]  = vld ? cnt : 0.f;
    }
}

// ---------------------------------------------------------------------------
// Kernel 2: pull loss (R10). Block = 1024 px; per thread 1 uchar4 + 4 float4
// (5 outstanding loads, ~45 VGPR -> 8 waves/SIMD). Grid 225x32 = 7200 blocks.
// Prologue loads the 6 precomputed means (L2-hot, ~tiny).
// ---------------------------------------------------------------------------
__global__ __launch_bounds__(256, 4) void pull_k(const unsigned char* __restrict__ tpk,
                                                 const float* __restrict__ emb,
                                                 const float* __restrict__ meansG,
                                                 const float* __restrict__ validG,
                                                 float* __restrict__ pullp) {
    __shared__ float4 lmean[L + 1];   // label 0 -> zero mean
    __shared__ float  lvalid[L + 1];  // label 0 -> invalid
    __shared__ float  lred[4];
    const int x = blockIdx.x, b = blockIdx.y;
    const int tid = threadIdx.x;
    const int lane = tid & 63, wave = tid >> 6;

    if (tid < L) {
        lmean[tid + 1]  = *(const float4*)(meansG + ((size_t)b * L + tid) * 4);
        lvalid[tid + 1] = validG[b * L + tid];
    }
    if (tid == L) { lmean[0] = make_float4(0.f, 0.f, 0.f, 0.f); lvalid[0] = 0.f; }
    __syncthreads();

    const uchar4* tp4 = (const uchar4*)(tpk + (size_t)b * P);
    const float4* e0  = (const float4*)(emb + ((size_t)b * C + 0) * P);
    const float4* e1  = (const float4*)(emb + ((size_t)b * C + 1) * P);
    const float4* e2  = (const float4*)(emb + ((size_t)b * C + 2) * P);
    const float4* e3  = (const float4*)(emb + ((size_t)b * C + 3) * P);

    const int g = x * 256 + tid;
    uchar4 t0 = tp4[g];
    float4 a0 = e0[g], a1 = e1[g], a2 = e2[g], a3 = e3[g];

    float acc = 0.f;
    auto proc1 = [&](int tt, float v0, float v1, float v2, float v3) {
        float4 m = lmean[tt];
        float d0 = v0 - m.x, d1 = v1 - m.y, d2 = v2 - m.z, d3 = v3 - m.w;
        float sq   = d0*d0 + d1*d1 + d2*d2 + d3*d3;
        float dist = sqrtf(fmaxf(sq, 1e-12f));
        float h    = fmaxf(dist - DELTA_V, 0.f);
        acc = fmaf(lvalid[tt] * h, h, acc);
    };
    proc1(t0.x, a0.x, a1.x, a2.x, a3.x);
    proc1(t0.y, a0.y, a1.y, a2.y, a3.y);
    proc1(t0.z, a0.z, a1.z, a2.z, a3.z);
    proc1(t0.w, a0.w, a1.w, a2.w, a3.w);

    float r = waveReduce(acc);
    if (lane == 0) lred[wave] = r;
    __syncthreads();
    if (tid == 0)
        pullp[b * CH1 + x] = lred[0] + lred[1] + lred[2] + lred[3];
}

// ---------------------------------------------------------------------------
// Kernel 3: final combine — push loss + point_count + pull partial sum
// ---------------------------------------------------------------------------
__global__ __launch_bounds__(256) void finish_k(const float* __restrict__ pullp,
                                                const float* __restrict__ meansG,
                                                const float* __restrict__ validG,
                                                const float* __restrict__ cntvG,
                                                float* __restrict__ out) {
    __shared__ float red[4][4];
    const int tid = threadIdx.x;
    const int lane = tid & 63, wave = tid >> 6;

    float vb = 0.f, has = 0.f;
    if (tid < B) {
        const float* mb = meansG + tid * L * 4;
        const float* vv = validG + tid * L;
        float ssum = 0.f, np = 0.f;
#pragma unroll
        for (int i = 0; i < L; ++i)
#pragma unroll
            for (int j = i + 1; j < L; ++j) {
                float ok = vv[i] * vv[j];
                float d0 = mb[i*4+0] - mb[j*4+0];
                float d1 = mb[i*4+1] - mb[j*4+1];
                float d2 = mb[i*4+2] - mb[j*4+2];
                float d3 = mb[i*4+3] - mb[j*4+3];
                float psq = d0*d0 + d1*d1 + d2*d2 + d3*d3;
                float pd  = sqrtf(fmaxf(psq, 1e-12f));
                float ph  = fmaxf(DELTA_D - pd, 0.f);
                ssum += ok * ph * ph;
                np   += ok;
            }
        if (np > 0.f) { vb = ssum / np; has = 1.f; }
    }
    float pc = (tid < B*L) ? cntvG[tid] : 0.f;
    float ps = 0.f;
    for (int i = tid; i < NBLK3; i += 256) ps += pullp[i];

    float rvb = waveReduce(vb);
    float rhs = waveReduce(has);
    float rpc = waveReduce(pc);
    float rps = waveReduce(ps);
    if (lane == 0) { red[wave][0]=rvb; red[wave][1]=rhs; red[wave][2]=rpc; red[wave][3]=rps; }
    __syncthreads();
    if (tid == 0) {
        float svb = red[0][0]+red[1][0]+red[2][0]+red[3][0];
        float shs = red[0][1]+red[1][1]+red[2][1]+red[3][1];
        float spc = red[0][2]+red[1][2]+red[2][2]+red[3][2];
        float sps = red[0][3]+red[1][3]+red[2][3]+red[3][3];
        float var = (shs > 0.f) ? svb / shs : 0.f;              // push loss
        float dl  = (spc > 0.f) ? sps / fmaxf(spc, 1.f) : 0.f;  // pull loss
        out[0] = dl + var;
    }
}

// ---------------------------------------------------------------------------
extern "C" void kernel_launch(void* const* d_in, const int* in_sizes, int n_in,
                              void* d_out, int out_size, void* d_ws, size_t ws_size,
                              hipStream_t stream) {
    const int*   tgt = (const int*)d_in[0];    // targets int32 [B,H,W]
    const float* emb = (const float*)d_in[1];  // embedding fp32 [B,C,H,W]

    // workspace layout: packed labels first (B*P bytes, 16B-aligned size),
    // then float scratch
    unsigned char* tpk = (unsigned char*)d_ws;                 // 7372800 B
    float* fbase   = (float*)((char*)d_ws + (size_t)B * P);    // 7372800 % 16 == 0
    float* partial = fbase;                                    // B*25*228 = 182400 floats
    float* meansG  = partial + (size_t)B * 25 * PSTR;          // 640 (16B-aligned)
    float* validG  = meansG + (size_t)B * L * 4;               // 160
    float* cntvG   = validG + B * L;                           // 160
    float* pullp   = cntvG + B * L;                            // 7200
    // total ws use: ~8.2 MB

    seg_sums_k<<<dim3(CH1, B), 256, 0, stream>>>(tgt, emb, partial, tpk);  // 7200 blocks
    means_k<<<dim3(B), 256, 0, stream>>>(partial, meansG, validG, cntvG);  // 32 blocks
    pull_k<<<dim3(CH1, B), 256, 0, stream>>>(tpk, emb, meansG, validG, pullp); // 7200 blocks
    finish_k<<<1, 256, 0, stream>>>(pullp, meansG, validG, cntvG, (float*)d_out);
}

// Round 4
// 229.363 us; speedup vs baseline: 1.0183x; 1.0183x over previous
//
#include <hip/hip_runtime.h>
#include <math.h>

// Problem constants (match reference)
#define B 32
#define C 4
#define P (360*640)        // 230400 pixels per batch
#define L 5                // MAX_LANES
#define DELTA_V 1.0f
#define DELTA_D 6.0f

// R11 shape: steady streaming loops, high occupancy, no load bursts.
#define CH 75              // chunks per batch -> grid (75,32) = 2400 blocks
#define I4 (P/(4*CH))      // 768 16B-vectors per chunk
#define IT1 (I4/64)        // 12 iterations per lane (K1, per-wave addressing)
#define IT2 (I4/256)       // 3 iterations per thread (K2, per-block addressing)
#define PSTR CH            // partial chunk-stride
#define NPULL (B*CH)       // 2400 pull partials

__device__ __forceinline__ float waveReduce(float v) {
#pragma unroll
    for (int off = 32; off; off >>= 1) v += __shfl_down(v, off, 64);
    return v;
}

// ---------------------------------------------------------------------------
// Kernel 1: segment sums. Channel-per-WAVE: wave w streams (labels, plane w)
// — 2 load streams per wave; label lines are L1 hits for waves 1-3. STEADY
// 12-iter loop (unroll 2) instead of the 25-load burst shape that plateaued
// at ~2 TB/s through R0-R3: loads stay continuously in flight. ~45 VGPR at
// (256,4) -> 8 blocks/CU resident, 32 waves/CU (vs 18% occupancy before).
// Each wave owns its 5 sums -> shuffle-reduce + direct global write, NO
// __syncthreads anywhere. Wave 0 also emits packed uint8 labels + counts.
// Partials VALUE-MAJOR: partial[(b*25+v)*PSTR+x], v=c*5+l (sums), 20+l (cnt).
// ---------------------------------------------------------------------------
__global__ __launch_bounds__(256, 4) void seg_sums_k(const int* __restrict__ tgt,
                                                     const float* __restrict__ emb,
                                                     float* __restrict__ partial,
                                                     unsigned char* __restrict__ tpk) {
    const int x = blockIdx.x, b = blockIdx.y;
    const int lane = threadIdx.x & 63, wave = threadIdx.x >> 6;

    const int4*   t4 = (const int4*)(tgt + (size_t)b * P) + (size_t)x * I4;
    const float4* ec = (const float4*)(emb + ((size_t)b * C + wave) * P) + (size_t)x * I4;
    uchar4*      tp4 = (uchar4*)(tpk + (size_t)b * P) + (size_t)x * I4;

    float s[L], n[L];
#pragma unroll
    for (int l = 0; l < L; ++l) { s[l] = 0.f; n[l] = 0.f; }

    auto elem = [&](int tt, float v) {
#pragma unroll
        for (int l = 0; l < L; ++l) {
            float m = (tt == l + 1) ? 1.0f : 0.0f;
            n[l] += m;
            s[l] = fmaf(m, v, s[l]);
        }
    };

#pragma unroll 2
    for (int it = 0; it < IT1; ++it) {
        const int g = it * 64 + lane;
        int4   t = t4[g];
        float4 e = ec[g];
        if (wave == 0)
            tp4[g] = make_uchar4((unsigned char)t.x, (unsigned char)t.y,
                                 (unsigned char)t.z, (unsigned char)t.w);
        elem(t.x, e.x);
        elem(t.y, e.y);
        elem(t.z, e.z);
        elem(t.w, e.w);
    }

    // per-wave shuffle reduce, direct global writes (no LDS, no syncthreads)
#pragma unroll
    for (int l = 0; l < L; ++l) {
        float r = waveReduce(s[l]);
        if (lane == 0) partial[((size_t)b * 25 + wave * L + l) * PSTR + x] = r;
    }
    if (wave == 0) {
#pragma unroll
        for (int l = 0; l < L; ++l) {
            float r = waveReduce(n[l]);
            if (lane == 0) partial[((size_t)b * 25 + 20 + l) * PSTR + x] = r;
        }
    }
}

// ---------------------------------------------------------------------------
// Kernel 1.5: reduce partials -> means/valid/counts. 32 blocks; wave w
// handles values w, w+4, ... (75 entries each). Tiny (~3-5 us).
// ---------------------------------------------------------------------------
__global__ __launch_bounds__(256) void means_k(const float* __restrict__ partial,
                                               float* __restrict__ meansG,
                                               float* __restrict__ validG,
                                               float* __restrict__ cntvG) {
    __shared__ float praw[25];
    const int b = blockIdx.x;
    const int tid = threadIdx.x;
    const int lane = tid & 63, wave = tid >> 6;

    for (int v = wave; v < 25; v += 4) {
        float sum = 0.f;
        for (int i = lane; i < CH; i += 64)
            sum += partial[((size_t)b * 25 + v) * PSTR + i];
        sum = waveReduce(sum);
        if (lane == 0) praw[v] = sum;
    }
    __syncthreads();
    if (tid < L) {
        const float cnt = praw[20 + tid];
        const bool  vld = cnt > 1.5f;          // integer count > 1
        const float inv = 1.0f / fmaxf(cnt, 1.0f);
        float4 m = make_float4(praw[tid] * inv, praw[5 + tid] * inv,
                               praw[10 + tid] * inv, praw[15 + tid] * inv);
        *(float4*)(meansG + ((size_t)b * L + tid) * 4) = m;
        validG[b * L + tid] = vld ? 1.f : 0.f;
        cntvG[b * L + tid]  = vld ? cnt : 0.f;
    }
}

// ---------------------------------------------------------------------------
// Kernel 2: pull loss. Steady 3-iter loop (unroll 2): per iter 1 uchar4 +
// 4 float4 (68 B/thread), acc scalar. ~40 VGPR at (256,4) -> 8 blocks/CU,
// 32 waves/CU. Means prologue reads the precomputed 6 entries (L2-hot).
// ---------------------------------------------------------------------------
__global__ __launch_bounds__(256, 4) void pull_k(const unsigned char* __restrict__ tpk,
                                                 const float* __restrict__ emb,
                                                 const float* __restrict__ meansG,
                                                 const float* __restrict__ validG,
                                                 float* __restrict__ pullp) {
    __shared__ float4 lmean[L + 1];   // label 0 -> zero mean
    __shared__ float  lvalid[L + 1];  // label 0 -> invalid
    __shared__ float  lred[4];
    const int x = blockIdx.x, b = blockIdx.y;
    const int tid = threadIdx.x;
    const int lane = tid & 63, wave = tid >> 6;

    if (tid < L) {
        lmean[tid + 1]  = *(const float4*)(meansG + ((size_t)b * L + tid) * 4);
        lvalid[tid + 1] = validG[b * L + tid];
    }
    if (tid == L) { lmean[0] = make_float4(0.f, 0.f, 0.f, 0.f); lvalid[0] = 0.f; }
    __syncthreads();

    const uchar4* tp4 = (const uchar4*)(tpk + (size_t)b * P) + (size_t)x * I4;
    const float4* e0  = (const float4*)(emb + ((size_t)b * C + 0) * P) + (size_t)x * I4;
    const float4* e1  = (const float4*)(emb + ((size_t)b * C + 1) * P) + (size_t)x * I4;
    const float4* e2  = (const float4*)(emb + ((size_t)b * C + 2) * P) + (size_t)x * I4;
    const float4* e3  = (const float4*)(emb + ((size_t)b * C + 3) * P) + (size_t)x * I4;

    float acc = 0.f;
    auto proc1 = [&](int tt, float v0, float v1, float v2, float v3) {
        float4 m = lmean[tt];
        float d0 = v0 - m.x, d1 = v1 - m.y, d2 = v2 - m.z, d3 = v3 - m.w;
        float sq   = d0*d0 + d1*d1 + d2*d2 + d3*d3;
        float dist = sqrtf(fmaxf(sq, 1e-12f));
        float h    = fmaxf(dist - DELTA_V, 0.f);
        acc = fmaf(lvalid[tt] * h, h, acc);
    };

#pragma unroll 2
    for (int it = 0; it < IT2; ++it) {
        const int g = it * 256 + tid;
        uchar4 t  = tp4[g];
        float4 a0 = e0[g], a1 = e1[g], a2 = e2[g], a3 = e3[g];
        proc1(t.x, a0.x, a1.x, a2.x, a3.x);
        proc1(t.y, a0.y, a1.y, a2.y, a3.y);
        proc1(t.z, a0.z, a1.z, a2.z, a3.z);
        proc1(t.w, a0.w, a1.w, a2.w, a3.w);
    }

    float r = waveReduce(acc);
    if (lane == 0) lred[wave] = r;
    __syncthreads();
    if (tid == 0)
        pullp[b * CH + x] = lred[0] + lred[1] + lred[2] + lred[3];
}

// ---------------------------------------------------------------------------
// Kernel 3: final combine — push loss + point_count + pull partial sum
// ---------------------------------------------------------------------------
__global__ __launch_bounds__(256) void finish_k(const float* __restrict__ pullp,
                                                const float* __restrict__ meansG,
                                                const float* __restrict__ validG,
                                                const float* __restrict__ cntvG,
                                                float* __restrict__ out) {
    __shared__ float red[4][4];
    const int tid = threadIdx.x;
    const int lane = tid & 63, wave = tid >> 6;

    float vb = 0.f, has = 0.f;
    if (tid < B) {
        const float* mb = meansG + tid * L * 4;
        const float* vv = validG + tid * L;
        float ssum = 0.f, np = 0.f;
#pragma unroll
        for (int i = 0; i < L; ++i)
#pragma unroll
            for (int j = i + 1; j < L; ++j) {
                float ok = vv[i] * vv[j];
                float d0 = mb[i*4+0] - mb[j*4+0];
                float d1 = mb[i*4+1] - mb[j*4+1];
                float d2 = mb[i*4+2] - mb[j*4+2];
                float d3 = mb[i*4+3] - mb[j*4+3];
                float psq = d0*d0 + d1*d1 + d2*d2 + d3*d3;
                float pd  = sqrtf(fmaxf(psq, 1e-12f));
                float ph  = fmaxf(DELTA_D - pd, 0.f);
                ssum += ok * ph * ph;
                np   += ok;
            }
        if (np > 0.f) { vb = ssum / np; has = 1.f; }
    }
    float pc = (tid < B*L) ? cntvG[tid] : 0.f;
    float ps = 0.f;
    for (int i = tid; i < NPULL; i += 256) ps += pullp[i];

    float rvb = waveReduce(vb);
    float rhs = waveReduce(has);
    float rpc = waveReduce(pc);
    float rps = waveReduce(ps);
    if (lane == 0) { red[wave][0]=rvb; red[wave][1]=rhs; red[wave][2]=rpc; red[wave][3]=rps; }
    __syncthreads();
    if (tid == 0) {
        float svb = red[0][0]+red[1][0]+red[2][0]+red[3][0];
        float shs = red[0][1]+red[1][1]+red[2][1]+red[3][1];
        float spc = red[0][2]+red[1][2]+red[2][2]+red[3][2];
        float sps = red[0][3]+red[1][3]+red[2][3]+red[3][3];
        float var = (shs > 0.f) ? svb / shs : 0.f;              // push loss
        float dl  = (spc > 0.f) ? sps / fmaxf(spc, 1.f) : 0.f;  // pull loss
        out[0] = dl + var;
    }
}

// ---------------------------------------------------------------------------
extern "C" void kernel_launch(void* const* d_in, const int* in_sizes, int n_in,
                              void* d_out, int out_size, void* d_ws, size_t ws_size,
                              hipStream_t stream) {
    const int*   tgt = (const int*)d_in[0];    // targets int32 [B,H,W]
    const float* emb = (const float*)d_in[1];  // embedding fp32 [B,C,H,W]

    // workspace layout: packed labels first (B*P bytes, 16B-aligned size),
    // then float scratch
    unsigned char* tpk = (unsigned char*)d_ws;                 // 7372800 B
    float* fbase   = (float*)((char*)d_ws + (size_t)B * P);    // 7372800 % 16 == 0
    float* partial = fbase;                                    // B*25*75 = 60000 floats
    float* meansG  = partial + (size_t)B * 25 * PSTR;          // 640 (16B-aligned)
    float* validG  = meansG + (size_t)B * L * 4;               // 160
    float* cntvG   = validG + B * L;                           // 160
    float* pullp   = cntvG + B * L;                            // 2400
    // total ws use: ~7.6 MB

    seg_sums_k<<<dim3(CH, B), 256, 0, stream>>>(tgt, emb, partial, tpk);   // 2400 blocks
    means_k<<<dim3(B), 256, 0, stream>>>(partial, meansG, validG, cntvG);  // 32 blocks
    pull_k<<<dim3(CH, B), 256, 0, stream>>>(tpk, emb, meansG, validG, pullp); // 2400 blocks
    finish_k<<<1, 256, 0, stream>>>(pullp, meansG, validG, cntvG, (float*)d_out);
}